// Round 4
// baseline (4082.120 us; speedup 1.0000x reference)
//
#include <hip/hip_runtime.h>
#include <cfloat>

// Problem constants (fixed by setup_inputs): B=64, S=2048, D=256, K=1024
#define DD 256
#define KK 1024
#define NROWS 131072            // B*S
#define QELEMS 33554432         // NROWS*DD
#define ROWS_PB 64
#define THETA 12.0f             // >= 2*eps_max(bf16 dot) ~ 3.8; 3x margin
#define CAND_MAX 16

typedef __attribute__((ext_vector_type(8))) short bf16x8;    // 8 bf16 = 4 VGPR
typedef __attribute__((ext_vector_type(16))) float f32x16;   // 32x32 acc

// round-to-nearest-even fp32 -> bf16
__device__ inline unsigned short rne_bf16(float f) {
    unsigned u = __float_as_uint(f);
    unsigned r = (u + 0x7fffu + ((u >> 16) & 1u)) >> 16;
    return (unsigned short)r;
}
// monotone float<->uint encoding for atomicMin on float values
__device__ inline unsigned fenc(float f) {
    unsigned u = __float_as_uint(f);
    return (u & 0x80000000u) ? ~u : (u | 0x80000000u);
}
__device__ inline float fdec(unsigned e) {
    return (e & 0x80000000u) ? __uint_as_float(e & 0x7fffffffu)
                             : __uint_as_float(~e);
}

// ---------------------------------------------------------------------------
// k_rowsq: dst[r] = sum(src[r,:]^2) replicating numpy pairwise_sum bit-exactly
// (unchanged from the verified kernel).
__global__ void k_rowsq(const float* __restrict__ src, float* __restrict__ dst,
                        int nrows) {
#pragma clang fp contract(off)
    const int lane = threadIdx.x & 63;
    const int wid = (blockIdx.x * blockDim.x + threadIdx.x) >> 6;
    if (wid >= nrows) return;
    float r = 0.0f;
    if (lane < 16) {
        const int half = lane >> 3, j = lane & 7;
        const float* a = src + (size_t)wid * DD + half * 128 + j;
        float v = a[0];
        r = v * v;
        for (int t = 1; t < 16; ++t) {
            float u = a[8 * t];
            float p = u * u;
            r = r + p;
        }
    }
    float o1 = __shfl_xor(r, 1); r = r + o1;
    float o2 = __shfl_xor(r, 2); r = r + o2;
    float o4 = __shfl_xor(r, 4); r = r + o4;
    float o8 = __shfl_xor(r, 8); r = r + o8;
    if (lane == 0) dst[wid] = r;
}

// ---------------------------------------------------------------------------
// k_prep: build cbh = bf16 codebook in MFMA-B-friendly layout [k/8][code][k%8]
// (so a fragment read is one contiguous ds_read_b128); zero hist / lossAcc.
__global__ void k_prep(const float* __restrict__ cb,
                       unsigned short* __restrict__ cbh,
                       int* __restrict__ hist, float* __restrict__ lossAcc) {
    const int code = blockIdx.x, k = threadIdx.x;
    cbh[(size_t)(k >> 3) * 8192 + code * 8 + (k & 7)] = rne_bf16(cb[code * DD + k]);
    if (code == 0) {
        for (int i = k; i < KK; i += 256) hist[i] = 0;
        if (k == 0) *lossAcc = 0.0f;
    }
}

// ---------------------------------------------------------------------------
// k2_gemm: bf16 MFMA scores s = c2 - 2*dot for 64 rows x 1024 codes/block,
// then per-row min + candidate list (codes within THETA of min) -> candBuf.
// 8 waves; wave w owns codes [w*128, w*128+128), all 64 rows.
// mfma_f32_32x32x16_bf16: A m=lane&31, k=(lane>>5)*8+e; B n=lane&31, same k;
// D col=lane&31, row=(reg&3)+8*(reg>>2)+4*(lane>>5) [verified mapping].
__global__ __launch_bounds__(512, 2) void k2_gemm(
    const float* __restrict__ x, const unsigned short* __restrict__ cbh,
    const float* __restrict__ c2, int* __restrict__ candBuf) {
    __shared__ unsigned short aL[16384];          // [kg 32][row 64][8]  32KB
    __shared__ unsigned short bL[16384];          // [kg 2][code 1024][8] 32KB
    __shared__ unsigned wmin[64];
    __shared__ int ccnt[64];
    __shared__ unsigned short clist[64][CAND_MAX];

    const int tid = threadIdx.x;
    const int lane = tid & 63;
    const int w = tid >> 6;                       // wave = code group
    const int row0 = blockIdx.x * 64;
    const int h = lane >> 5;                      // k-half within fragment
    const int l31 = lane & 31;

    if (tid < 64) { wmin[tid] = 0xFFFFFFFFu; ccnt[tid] = 0; }

    {   // stage A: 64 rows x 256 k, fp32 -> bf16 RNE, layout [k/8][row][8]
        const float4* xg = (const float4*)(x + (size_t)row0 * DD);
#pragma unroll
        for (int i = 0; i < 8; ++i) {
            int lin = tid + i * 512;              // 0..4095 float4s
            int r = lin >> 6, c4 = lin & 63;      // k = c4*4..+3
            float4 v = xg[lin];
            unsigned p0 = (unsigned)rne_bf16(v.x) | ((unsigned)rne_bf16(v.y) << 16);
            unsigned p1 = (unsigned)rne_bf16(v.z) | ((unsigned)rne_bf16(v.w) << 16);
            unsigned short* p = &aL[(c4 >> 1) * 512 + r * 8 + (c4 & 1) * 4];
            *(uint2*)p = make_uint2(p0, p1);
        }
    }

    // B k-step staging through registers (single buffer, double barrier)
    const bf16x8* cb8 = (const bf16x8*)cbh;       // 2048 chunks per k-step
    bf16x8 st0 = cb8[tid], st1 = cb8[tid + 512],
           st2 = cb8[tid + 1024], st3 = cb8[tid + 1536];
    __syncthreads();
    {
        bf16x8* bw = (bf16x8*)bL;
        bw[tid] = st0; bw[tid + 512] = st1;
        bw[tid + 1024] = st2; bw[tid + 1536] = st3;
    }
    __syncthreads();

    f32x16 acc[2][4];
#pragma unroll
    for (int rf = 0; rf < 2; ++rf)
#pragma unroll
        for (int cf = 0; cf < 4; ++cf)
#pragma unroll
            for (int e = 0; e < 16; ++e) acc[rf][cf][e] = 0.0f;

    const int aoff0 = l31 * 8;
    const int aoff1 = (32 + l31) * 8;
    const int boff = h * 8192 + (w * 128 + l31) * 8;

    for (int ks = 0; ks < 16; ++ks) {             // K = 256 = 16 x 16
        if (ks < 15) {                            // prefetch next B slice
            int base = (ks + 1) * 2048 + tid;
            st0 = cb8[base]; st1 = cb8[base + 512];
            st2 = cb8[base + 1024]; st3 = cb8[base + 1536];
        }
        const int ab = (2 * ks + h) * 512;
        bf16x8 av0 = *(const bf16x8*)(&aL[ab + aoff0]);
        bf16x8 av1 = *(const bf16x8*)(&aL[ab + aoff1]);
#pragma unroll
        for (int cf = 0; cf < 4; ++cf) {
            bf16x8 bv = *(const bf16x8*)(&bL[boff + cf * 256]);
            acc[0][cf] = __builtin_amdgcn_mfma_f32_32x32x16_bf16(av0, bv, acc[0][cf], 0, 0, 0);
            acc[1][cf] = __builtin_amdgcn_mfma_f32_32x32x16_bf16(av1, bv, acc[1][cf], 0, 0, 0);
        }
        __syncthreads();                          // all reads of bL done
        if (ks < 15) {
            bf16x8* bw = (bf16x8*)bL;
            bw[tid] = st0; bw[tid + 512] = st1;
            bw[tid + 1024] = st2; bw[tid + 1536] = st3;
            __syncthreads();                      // next slice visible
        }
    }

    // scores in place: s = c2_exact - 2*dot_bf16
    float c2v[4];
#pragma unroll
    for (int cf = 0; cf < 4; ++cf) c2v[cf] = c2[w * 128 + cf * 32 + l31];
#pragma unroll
    for (int rf = 0; rf < 2; ++rf)
#pragma unroll
        for (int cf = 0; cf < 4; ++cf)
#pragma unroll
            for (int e = 0; e < 16; ++e)
                acc[rf][cf][e] = fmaf(-2.0f, acc[rf][cf][e], c2v[cf]);

    // pass 1: per-row block-wide min via shfl + LDS atomicMin
#pragma unroll
    for (int rf = 0; rf < 2; ++rf)
#pragma unroll
        for (int r = 0; r < 16; ++r) {
            float v = fminf(fminf(acc[rf][0][r], acc[rf][1][r]),
                            fminf(acc[rf][2][r], acc[rf][3][r]));
            v = fminf(v, __shfl_xor(v, 1));
            v = fminf(v, __shfl_xor(v, 2));
            v = fminf(v, __shfl_xor(v, 4));
            v = fminf(v, __shfl_xor(v, 8));
            v = fminf(v, __shfl_xor(v, 16));
            if (l31 == 0)
                atomicMin(&wmin[rf * 32 + (r & 3) + 8 * (r >> 2) + 4 * h], fenc(v));
        }
    __syncthreads();

    // pass 2: collect candidates within THETA of the row min
#pragma unroll
    for (int rf = 0; rf < 2; ++rf)
#pragma unroll
        for (int r = 0; r < 16; ++r) {
            int rr = rf * 32 + (r & 3) + 8 * (r >> 2) + 4 * h;
            float gm = fdec(wmin[rr]) + THETA;
#pragma unroll
            for (int cf = 0; cf < 4; ++cf) {
                if (acc[rf][cf][r] <= gm) {
                    int pos = atomicAdd(&ccnt[rr], 1);
                    if (pos < CAND_MAX)
                        clist[rr][pos] = (unsigned short)(w * 128 + cf * 32 + l31);
                }
            }
        }
    __syncthreads();

    if (tid < 64) {
        int* o = candBuf + (size_t)(row0 + tid) * (CAND_MAX + 1);
        o[0] = ccnt[tid];
#pragma unroll
        for (int i = 0; i < CAND_MAX; ++i) o[1 + i] = clist[tid][i];
    }
}

// ---------------------------------------------------------------------------
// k_recheck: exact fp32 re-evaluation of candidates with the reference
// rounding lattice (pairwise x2, serial ascending-d fmaf dot,
// fl(fl(x2+c2) - 2*dot)); lexicographic (s, k) min = first-index argmin.
__global__ __launch_bounds__(256) void k_recheck(
    const float* __restrict__ x, const float* __restrict__ cb,
    const float* __restrict__ c2, const int* __restrict__ candBuf,
    float* __restrict__ outIdx, int* __restrict__ hist,
    float* __restrict__ lossAcc) {
#pragma clang fp contract(off)
    __shared__ float xsT[DD * 65];                // [d][row], pad-65
    const int tid = threadIdx.x;
    const int row0 = blockIdx.x * 64;
    {
        const float4* xg = (const float4*)(x + (size_t)row0 * DD);
#pragma unroll
        for (int i = 0; i < 16; ++i) {
            int lin = tid + i * 256;
            int r = lin >> 6, c4 = lin & 63;
            float4 v = xg[lin];
            xsT[(c4 * 4 + 0) * 65 + r] = v.x;
            xsT[(c4 * 4 + 1) * 65 + r] = v.y;
            xsT[(c4 * 4 + 2) * 65 + r] = v.z;
            xsT[(c4 * 4 + 3) * 65 + r] = v.w;
        }
    }
    __syncthreads();
    if (tid < 64) {
        const int row = tid;
        // exact x2: np pairwise (two 128-halves, 8 stride-8 accs x16 serial)
        float hsum[2];
#pragma unroll
        for (int hh = 0; hh < 2; ++hh) {
            float a[8];
#pragma unroll
            for (int j = 0; j < 8; ++j) {
                float v = xsT[(hh * 128 + j) * 65 + row];
                a[j] = v * v;
            }
            for (int t = 1; t < 16; ++t) {
#pragma unroll
                for (int j = 0; j < 8; ++j) {
                    float u = xsT[(hh * 128 + j + 8 * t) * 65 + row];
                    float p = u * u;
                    a[j] = a[j] + p;
                }
            }
            float s01 = a[0] + a[1], s23 = a[2] + a[3];
            float s45 = a[4] + a[5], s67 = a[6] + a[7];
            hsum[hh] = (s01 + s23) + (s45 + s67);
        }
        const float x2v = hsum[0] + hsum[1];

        const int* cd = candBuf + (size_t)(row0 + row) * (CAND_MAX + 1);
        int n = cd[0];
        float bs = FLT_MAX;
        int bk = 0x7fffffff;
        if (n <= CAND_MAX) {
            for (int i = 0; i < n; ++i) {
                int k = cd[1 + i];
                const float* cr = cb + (size_t)k * DD;
                float dot = 0.0f;
#pragma unroll 8
                for (int d = 0; d < DD; ++d)
                    dot = fmaf(xsT[d * 65 + row], cr[d], dot);
                float T1 = x2v + c2[k];
                float s = fmaf(-2.0f, dot, T1);
                if (s < bs || (s == bs && k < bk)) { bs = s; bk = k; }
            }
        } else {                                   // overflow: full exact scan
            for (int k = 0; k < KK; ++k) {
                const float* cr = cb + (size_t)k * DD;
                float dot = 0.0f;
#pragma unroll 8
                for (int d = 0; d < DD; ++d)
                    dot = fmaf(xsT[d * 65 + row], cr[d], dot);
                float T1 = x2v + c2[k];
                float s = fmaf(-2.0f, dot, T1);
                if (s < bs || (s == bs && k < bk)) { bs = s; bk = k; }
            }
        }
        outIdx[row0 + row] = (float)bk;
        atomicAdd(hist + bk, 1);
        float ls = bs;
#pragma unroll
        for (int off = 32; off > 0; off >>= 1) ls += __shfl_down(ls, off);
        if (tid == 0) atomicAdd(lossAcc, ls);
    }
}

// ---------------------------------------------------------------------------
// K3: pure gather -> outQ (unchanged).
__global__ __launch_bounds__(256) void k3_gather(
    const float* __restrict__ cb, const float* __restrict__ outIdx,
    float* __restrict__ outQ) {
    __shared__ int sidx[ROWS_PB];
    const int t = threadIdx.x;
    const int row0 = blockIdx.x * ROWS_PB;
    if (t < ROWS_PB) sidx[t] = (int)outIdx[row0 + t];
    __syncthreads();

    float4* q4 = (float4*)(outQ + (size_t)row0 * DD);
    const float4* c4 = (const float4*)cb;
#pragma unroll
    for (int i = 0; i < 16; ++i) {
        int lin = t + i * 256;
        int r = lin >> 6;
        int c = lin & 63;
        q4[lin] = c4[(size_t)sidx[r] * 64 + c];
    }
}

// ---------------------------------------------------------------------------
// K4: finalize loss + perplexity (unchanged).
__global__ void k4_final(const int* __restrict__ hist,
                         const float* __restrict__ lossAcc,
                         float* __restrict__ outLoss,
                         float* __restrict__ outPerp) {
    __shared__ float red[256];
    const int t = threadIdx.x;
    float e = 0.0f;
    for (int i = t; i < KK; i += 256) {
        float p = (float)hist[i] * (1.0f / (float)NROWS);
        e -= p * logf(p + 1e-10f);
    }
    red[t] = e;
    __syncthreads();
    for (int s = 128; s > 0; s >>= 1) {
        if (t < s) red[t] += red[t + s];
        __syncthreads();
    }
    if (t == 0) {
        *outPerp = expf(red[0]);
        *outLoss = 1.25f * (*lossAcc) / (float)QELEMS;
    }
}

// ---------------------------------------------------------------------------
extern "C" void kernel_launch(void* const* d_in, const int* in_sizes, int n_in,
                              void* d_out, int out_size, void* d_ws, size_t ws_size,
                              hipStream_t stream) {
    const float* x = (const float*)d_in[0];    // [131072, 256]
    const float* cb = (const float*)d_in[1];   // [1024, 256]

    float* outQ = (float*)d_out;               // 33554432
    float* outIdx = outQ + QELEMS;             // 131072
    float* outLoss = outIdx + NROWS;           // 1
    float* outPerp = outLoss + 1;              // 1

    // ws (~532KB): cbh bf16 [32][1024][8], c2, hist, lossAcc
    unsigned short* cbh = (unsigned short*)d_ws;
    float* c2 = (float*)((char*)d_ws + 524288);
    int* hist = (int*)(c2 + KK);
    float* lossAcc = (float*)(hist + KK);
    // candidate buffer lives in outQ's space (8.9MB of 128MB); it is fully
    // consumed by k_recheck before k3_gather overwrites outQ (stream order).
    int* candBuf = (int*)outQ;

    k_rowsq<<<dim3(KK / 4), dim3(256), 0, stream>>>(cb, c2, KK);
    k_prep<<<dim3(KK), dim3(256), 0, stream>>>(cb, cbh, hist, lossAcc);
    k2_gemm<<<dim3(NROWS / 64), dim3(512), 0, stream>>>(x, cbh, c2, candBuf);
    k_recheck<<<dim3(NROWS / 64), dim3(256), 0, stream>>>(x, cb, c2, candBuf,
                                                          outIdx, hist, lossAcc);
    k3_gather<<<dim3(NROWS / ROWS_PB), dim3(256), 0, stream>>>(cb, outIdx, outQ);
    k4_final<<<dim3(1), dim3(256), 0, stream>>>(hist, lossAcc, outLoss, outPerp);
}

// Round 5
// 553.651 us; speedup vs baseline: 7.3731x; 7.3731x over previous
//
#include <hip/hip_runtime.h>
#include <cfloat>

// Problem constants (fixed by setup_inputs): B=64, S=2048, D=256, K=1024
#define DD 256
#define KK 1024
#define NROWS 131072            // B*S
#define QELEMS 33554432         // NROWS*DD
#define ROWS_PB 64
#define THETA 12.0f             // >= 2*eps_max(bf16 dot) ~ 3.8; 3x margin
#define CAND_MAX 16

typedef __attribute__((ext_vector_type(8))) short bf16x8;    // 8 bf16 = 4 VGPR
typedef __attribute__((ext_vector_type(16))) float f32x16;   // 32x32 acc

// round-to-nearest-even fp32 -> bf16
__device__ inline unsigned short rne_bf16(float f) {
    unsigned u = __float_as_uint(f);
    unsigned r = (u + 0x7fffu + ((u >> 16) & 1u)) >> 16;
    return (unsigned short)r;
}
// monotone float<->uint encoding for atomicMin on float values
__device__ inline unsigned fenc(float f) {
    unsigned u = __float_as_uint(f);
    return (u & 0x80000000u) ? ~u : (u | 0x80000000u);
}
__device__ inline float fdec(unsigned e) {
    return (e & 0x80000000u) ? __uint_as_float(e & 0x7fffffffu)
                             : __uint_as_float(~e);
}

// ---------------------------------------------------------------------------
// k_rowsq: dst[r] = sum(src[r,:]^2) replicating numpy pairwise_sum bit-exactly
// (unchanged from the verified kernel).
__global__ void k_rowsq(const float* __restrict__ src, float* __restrict__ dst,
                        int nrows) {
#pragma clang fp contract(off)
    const int lane = threadIdx.x & 63;
    const int wid = (blockIdx.x * blockDim.x + threadIdx.x) >> 6;
    if (wid >= nrows) return;
    float r = 0.0f;
    if (lane < 16) {
        const int half = lane >> 3, j = lane & 7;
        const float* a = src + (size_t)wid * DD + half * 128 + j;
        float v = a[0];
        r = v * v;
        for (int t = 1; t < 16; ++t) {
            float u = a[8 * t];
            float p = u * u;
            r = r + p;
        }
    }
    float o1 = __shfl_xor(r, 1); r = r + o1;
    float o2 = __shfl_xor(r, 2); r = r + o2;
    float o4 = __shfl_xor(r, 4); r = r + o4;
    float o8 = __shfl_xor(r, 8); r = r + o8;
    if (lane == 0) dst[wid] = r;
}

// ---------------------------------------------------------------------------
// k_prep: build cbh = bf16 codebook in MFMA-B-friendly layout [k/8][code][k%8]
// (so a fragment read is one contiguous ds_read_b128); zero hist / lossAcc.
__global__ void k_prep(const float* __restrict__ cb,
                       unsigned short* __restrict__ cbh,
                       int* __restrict__ hist, float* __restrict__ lossAcc) {
    const int code = blockIdx.x, k = threadIdx.x;
    cbh[(size_t)(k >> 3) * 8192 + code * 8 + (k & 7)] = rne_bf16(cb[code * DD + k]);
    if (code == 0) {
        for (int i = k; i < KK; i += 256) hist[i] = 0;
        if (k == 0) *lossAcc = 0.0f;
    }
}

// ---------------------------------------------------------------------------
// k2_gemm: bf16 MFMA scores s = c2 - 2*dot for 64 rows x 1024 codes/block,
// then per-row min + candidate list (codes within THETA of min) -> candBuf.
// (unchanged from round 4 -- verified correct end-to-end)
__global__ __launch_bounds__(512, 2) void k2_gemm(
    const float* __restrict__ x, const unsigned short* __restrict__ cbh,
    const float* __restrict__ c2, int* __restrict__ candBuf) {
    __shared__ unsigned short aL[16384];          // [kg 32][row 64][8]  32KB
    __shared__ unsigned short bL[16384];          // [kg 2][code 1024][8] 32KB
    __shared__ unsigned wmin[64];
    __shared__ int ccnt[64];
    __shared__ unsigned short clist[64][CAND_MAX];

    const int tid = threadIdx.x;
    const int lane = tid & 63;
    const int w = tid >> 6;                       // wave = code group
    const int row0 = blockIdx.x * 64;
    const int h = lane >> 5;                      // k-half within fragment
    const int l31 = lane & 31;

    if (tid < 64) { wmin[tid] = 0xFFFFFFFFu; ccnt[tid] = 0; }

    {   // stage A: 64 rows x 256 k, fp32 -> bf16 RNE, layout [k/8][row][8]
        const float4* xg = (const float4*)(x + (size_t)row0 * DD);
#pragma unroll
        for (int i = 0; i < 8; ++i) {
            int lin = tid + i * 512;              // 0..4095 float4s
            int r = lin >> 6, c4 = lin & 63;      // k = c4*4..+3
            float4 v = xg[lin];
            unsigned p0 = (unsigned)rne_bf16(v.x) | ((unsigned)rne_bf16(v.y) << 16);
            unsigned p1 = (unsigned)rne_bf16(v.z) | ((unsigned)rne_bf16(v.w) << 16);
            unsigned short* p = &aL[(c4 >> 1) * 512 + r * 8 + (c4 & 1) * 4];
            *(uint2*)p = make_uint2(p0, p1);
        }
    }

    // B k-step staging through registers (single buffer, double barrier)
    const bf16x8* cb8 = (const bf16x8*)cbh;       // 2048 chunks per k-step
    bf16x8 st0 = cb8[tid], st1 = cb8[tid + 512],
           st2 = cb8[tid + 1024], st3 = cb8[tid + 1536];
    __syncthreads();
    {
        bf16x8* bw = (bf16x8*)bL;
        bw[tid] = st0; bw[tid + 512] = st1;
        bw[tid + 1024] = st2; bw[tid + 1536] = st3;
    }
    __syncthreads();

    f32x16 acc[2][4];
#pragma unroll
    for (int rf = 0; rf < 2; ++rf)
#pragma unroll
        for (int cf = 0; cf < 4; ++cf)
#pragma unroll
            for (int e = 0; e < 16; ++e) acc[rf][cf][e] = 0.0f;

    const int aoff0 = l31 * 8;
    const int aoff1 = (32 + l31) * 8;
    const int boff = h * 8192 + (w * 128 + l31) * 8;

    for (int ks = 0; ks < 16; ++ks) {             // K = 256 = 16 x 16
        if (ks < 15) {                            // prefetch next B slice
            int base = (ks + 1) * 2048 + tid;
            st0 = cb8[base]; st1 = cb8[base + 512];
            st2 = cb8[base + 1024]; st3 = cb8[base + 1536];
        }
        const int ab = (2 * ks + h) * 512;
        bf16x8 av0 = *(const bf16x8*)(&aL[ab + aoff0]);
        bf16x8 av1 = *(const bf16x8*)(&aL[ab + aoff1]);
#pragma unroll
        for (int cf = 0; cf < 4; ++cf) {
            bf16x8 bv = *(const bf16x8*)(&bL[boff + cf * 256]);
            acc[0][cf] = __builtin_amdgcn_mfma_f32_32x32x16_bf16(av0, bv, acc[0][cf], 0, 0, 0);
            acc[1][cf] = __builtin_amdgcn_mfma_f32_32x32x16_bf16(av1, bv, acc[1][cf], 0, 0, 0);
        }
        __syncthreads();                          // all reads of bL done
        if (ks < 15) {
            bf16x8* bw = (bf16x8*)bL;
            bw[tid] = st0; bw[tid + 512] = st1;
            bw[tid + 1024] = st2; bw[tid + 1536] = st3;
            __syncthreads();                      // next slice visible
        }
    }

    // scores in place: s = c2_exact - 2*dot_bf16
    float c2v[4];
#pragma unroll
    for (int cf = 0; cf < 4; ++cf) c2v[cf] = c2[w * 128 + cf * 32 + l31];
#pragma unroll
    for (int rf = 0; rf < 2; ++rf)
#pragma unroll
        for (int cf = 0; cf < 4; ++cf)
#pragma unroll
            for (int e = 0; e < 16; ++e)
                acc[rf][cf][e] = fmaf(-2.0f, acc[rf][cf][e], c2v[cf]);

    // pass 1: per-row block-wide min via shfl + LDS atomicMin
#pragma unroll
    for (int rf = 0; rf < 2; ++rf)
#pragma unroll
        for (int r = 0; r < 16; ++r) {
            float v = fminf(fminf(acc[rf][0][r], acc[rf][1][r]),
                            fminf(acc[rf][2][r], acc[rf][3][r]));
            v = fminf(v, __shfl_xor(v, 1));
            v = fminf(v, __shfl_xor(v, 2));
            v = fminf(v, __shfl_xor(v, 4));
            v = fminf(v, __shfl_xor(v, 8));
            v = fminf(v, __shfl_xor(v, 16));
            if (l31 == 0)
                atomicMin(&wmin[rf * 32 + (r & 3) + 8 * (r >> 2) + 4 * h], fenc(v));
        }
    __syncthreads();

    // pass 2: collect candidates within THETA of the row min
#pragma unroll
    for (int rf = 0; rf < 2; ++rf)
#pragma unroll
        for (int r = 0; r < 16; ++r) {
            int rr = rf * 32 + (r & 3) + 8 * (r >> 2) + 4 * h;
            float gm = fdec(wmin[rr]) + THETA;
#pragma unroll
            for (int cf = 0; cf < 4; ++cf) {
                if (acc[rf][cf][r] <= gm) {
                    int pos = atomicAdd(&ccnt[rr], 1);
                    if (pos < CAND_MAX)
                        clist[rr][pos] = (unsigned short)(w * 128 + cf * 32 + l31);
                }
            }
        }
    __syncthreads();

    if (tid < 64) {
        int* o = candBuf + (size_t)(row0 + tid) * (CAND_MAX + 1);
        o[0] = ccnt[tid];
#pragma unroll
        for (int i = 0; i < CAND_MAX; ++i) o[1 + i] = clist[tid][i];
    }
}

// ---------------------------------------------------------------------------
// k_recheck (REWRITTEN): block-balanced worklist of (row, cand) pairs
// consumed by all 256 threads; per-row exact lexicographic (s,k) min via
// two-pass 32-bit LDS atomicMin. Overflow rows (n > CAND_MAX) handled
// block-cooperatively (256 threads x 4 codes each) instead of one serial
// lane scanning 1024 codes (the round-4 straggler: one such row = 6ms).
// Exact lattice unchanged: pairwise x2, ascending-d serial fmaf dot,
// s = fmaf(-2, dot, fl(x2 + c2)).
__global__ __launch_bounds__(256) void k_recheck(
    const float* __restrict__ x, const float* __restrict__ cb,
    const float* __restrict__ c2, const int* __restrict__ candBuf,
    float* __restrict__ outIdx, int* __restrict__ hist,
    float* __restrict__ lossAcc) {
#pragma clang fp contract(off)
    __shared__ float xsT[DD * 65];                // [d][row], pad-65: 66,560B
    __shared__ float x2s[64];
    __shared__ unsigned bestS[64];
    __shared__ int bestK[64];
    __shared__ int wl[64 * CAND_MAX];             // (row<<16)|k
    __shared__ float wls[64 * CAND_MAX];          // exact s per item
    __shared__ int ovf[64];
    __shared__ int wln, ovfn;

    const int tid = threadIdx.x;
    const int row0 = blockIdx.x * 64;

    if (tid < 64) { bestS[tid] = 0xFFFFFFFFu; bestK[tid] = 0x7fffffff; }
    if (tid == 0) { wln = 0; ovfn = 0; }

    {   // stage 64 rows transposed
        const float4* xg = (const float4*)(x + (size_t)row0 * DD);
#pragma unroll
        for (int i = 0; i < 16; ++i) {
            int lin = tid + i * 256;
            int r = lin >> 6, c4 = lin & 63;
            float4 v = xg[lin];
            xsT[(c4 * 4 + 0) * 65 + r] = v.x;
            xsT[(c4 * 4 + 1) * 65 + r] = v.y;
            xsT[(c4 * 4 + 2) * 65 + r] = v.z;
            xsT[(c4 * 4 + 3) * 65 + r] = v.w;
        }
    }
    __syncthreads();

    // exact x2 per row (np pairwise lattice) + worklist build
    if (tid < 64) {
        const int row = tid;
        float hsum[2];
#pragma unroll
        for (int hh = 0; hh < 2; ++hh) {
            float a[8];
#pragma unroll
            for (int j = 0; j < 8; ++j) {
                float v = xsT[(hh * 128 + j) * 65 + row];
                a[j] = v * v;
            }
            for (int t = 1; t < 16; ++t) {
#pragma unroll
                for (int j = 0; j < 8; ++j) {
                    float u = xsT[(hh * 128 + j + 8 * t) * 65 + row];
                    float p = u * u;
                    a[j] = a[j] + p;
                }
            }
            float s01 = a[0] + a[1], s23 = a[2] + a[3];
            float s45 = a[4] + a[5], s67 = a[6] + a[7];
            hsum[hh] = (s01 + s23) + (s45 + s67);
        }
        x2s[row] = hsum[0] + hsum[1];

        const int* cd = candBuf + (size_t)(row0 + row) * (CAND_MAX + 1);
        int n = cd[0];
        if (n <= CAND_MAX) {
            int base = atomicAdd(&wln, n);
            for (int i = 0; i < n; ++i) wl[base + i] = (row << 16) | cd[1 + i];
        } else {
            ovf[atomicAdd(&ovfn, 1)] = row;       // incomplete list: full scan
        }
    }
    __syncthreads();

    const int NW = wln;
    const int NO = ovfn;

    // pass A: exact s per item, per-row min via encoded atomicMin
    for (int it = tid; it < NW; it += 256) {
        const int row = wl[it] >> 16, k = wl[it] & 0xFFFF;
        const float* cr = cb + (size_t)k * DD;
        float dot = 0.0f;
#pragma unroll 8
        for (int d = 0; d < DD; ++d)
            dot = fmaf(xsT[d * 65 + row], cr[d], dot);
        float T1 = x2s[row] + c2[k];
        float s = fmaf(-2.0f, dot, T1);
        wls[it] = s;
        atomicMin(&bestS[row], fenc(s));
    }
    __syncthreads();

    // pass B: smallest index among s == row min (first-index argmin)
    for (int it = tid; it < NW; it += 256) {
        const int row = wl[it] >> 16, k = wl[it] & 0xFFFF;
        if (fenc(wls[it]) == bestS[row]) atomicMin(&bestK[row], k);
    }

    // overflow rows: block-cooperative exact full scan (4 codes per thread)
    for (int o = 0; o < NO; ++o) {
        __syncthreads();
        const int row = ovf[o];
        float myS[4];
#pragma unroll
        for (int q = 0; q < 4; ++q) {
            const int k = tid + q * 256;
            const float* cr = cb + (size_t)k * DD;
            float dot = 0.0f;
#pragma unroll 8
            for (int d = 0; d < DD; ++d)
                dot = fmaf(xsT[d * 65 + row], cr[d], dot);   // LDS broadcast
            float T1 = x2s[row] + c2[k];
            myS[q] = fmaf(-2.0f, dot, T1);
            atomicMin(&bestS[row], fenc(myS[q]));
        }
        __syncthreads();
#pragma unroll
        for (int q = 0; q < 4; ++q)
            if (fenc(myS[q]) == bestS[row]) atomicMin(&bestK[row], tid + q * 256);
    }
    __syncthreads();

    if (tid < 64) {
        const float bs = fdec(bestS[tid]);
        const int bk = bestK[tid];
        outIdx[row0 + tid] = (float)bk;
        atomicAdd(hist + bk, 1);
        float ls = bs;
#pragma unroll
        for (int off = 32; off > 0; off >>= 1) ls += __shfl_down(ls, off);
        if (tid == 0) atomicAdd(lossAcc, ls);
    }
}

// ---------------------------------------------------------------------------
// K3: pure gather -> outQ (unchanged).
__global__ __launch_bounds__(256) void k3_gather(
    const float* __restrict__ cb, const float* __restrict__ outIdx,
    float* __restrict__ outQ) {
    __shared__ int sidx[ROWS_PB];
    const int t = threadIdx.x;
    const int row0 = blockIdx.x * ROWS_PB;
    if (t < ROWS_PB) sidx[t] = (int)outIdx[row0 + t];
    __syncthreads();

    float4* q4 = (float4*)(outQ + (size_t)row0 * DD);
    const float4* c4 = (const float4*)cb;
#pragma unroll
    for (int i = 0; i < 16; ++i) {
        int lin = t + i * 256;
        int r = lin >> 6;
        int c = lin & 63;
        q4[lin] = c4[(size_t)sidx[r] * 64 + c];
    }
}

// ---------------------------------------------------------------------------
// K4: finalize loss + perplexity (unchanged).
__global__ void k4_final(const int* __restrict__ hist,
                         const float* __restrict__ lossAcc,
                         float* __restrict__ outLoss,
                         float* __restrict__ outPerp) {
    __shared__ float red[256];
    const int t = threadIdx.x;
    float e = 0.0f;
    for (int i = t; i < KK; i += 256) {
        float p = (float)hist[i] * (1.0f / (float)NROWS);
        e -= p * logf(p + 1e-10f);
    }
    red[t] = e;
    __syncthreads();
    for (int s = 128; s > 0; s >>= 1) {
        if (t < s) red[t] += red[t + s];
        __syncthreads();
    }
    if (t == 0) {
        *outPerp = expf(red[0]);
        *outLoss = 1.25f * (*lossAcc) / (float)QELEMS;
    }
}

// ---------------------------------------------------------------------------
extern "C" void kernel_launch(void* const* d_in, const int* in_sizes, int n_in,
                              void* d_out, int out_size, void* d_ws, size_t ws_size,
                              hipStream_t stream) {
    const float* x = (const float*)d_in[0];    // [131072, 256]
    const float* cb = (const float*)d_in[1];   // [1024, 256]

    float* outQ = (float*)d_out;               // 33554432
    float* outIdx = outQ + QELEMS;             // 131072
    float* outLoss = outIdx + NROWS;           // 1
    float* outPerp = outLoss + 1;              // 1

    // ws (~532KB): cbh bf16 [32][1024][8], c2, hist, lossAcc
    unsigned short* cbh = (unsigned short*)d_ws;
    float* c2 = (float*)((char*)d_ws + 524288);
    int* hist = (int*)(c2 + KK);
    float* lossAcc = (float*)(hist + KK);
    // candidate buffer lives in outQ's space (8.9MB of 128MB); it is fully
    // consumed by k_recheck before k3_gather overwrites outQ (stream order).
    int* candBuf = (int*)outQ;

    k_rowsq<<<dim3(KK / 4), dim3(256), 0, stream>>>(cb, c2, KK);
    k_prep<<<dim3(KK), dim3(256), 0, stream>>>(cb, cbh, hist, lossAcc);
    k2_gemm<<<dim3(NROWS / 64), dim3(512), 0, stream>>>(x, cbh, c2, candBuf);
    k_recheck<<<dim3(NROWS / 64), dim3(256), 0, stream>>>(x, cb, c2, candBuf,
                                                          outIdx, hist, lossAcc);
    k3_gather<<<dim3(NROWS / ROWS_PB), dim3(256), 0, stream>>>(cb, outIdx, outQ);
    k4_final<<<dim3(1), dim3(256), 0, stream>>>(hist, lossAcc, outLoss, outPerp);
}

// Round 6
// 536.628 us; speedup vs baseline: 7.6070x; 1.0317x over previous
//
#include <hip/hip_runtime.h>
#include <cfloat>

// Problem constants (fixed by setup_inputs): B=64, S=2048, D=256, K=1024
#define DD 256
#define KK 1024
#define NROWS 131072            // B*S
#define QELEMS 33554432         // NROWS*DD
#define ROWS_PB 64
#define THETA 12.0f             // >= 2*eps_max(bf16 dot) ~ 3.8; 3x margin
#define CAND_MAX 16

typedef __attribute__((ext_vector_type(8))) short bf16x8;    // 8 bf16 = 4 VGPR
typedef __attribute__((ext_vector_type(16))) float f32x16;   // 32x32 acc

// round-to-nearest-even fp32 -> bf16
__device__ inline unsigned short rne_bf16(float f) {
    unsigned u = __float_as_uint(f);
    unsigned r = (u + 0x7fffu + ((u >> 16) & 1u)) >> 16;
    return (unsigned short)r;
}
// monotone float<->uint encoding for atomicMin on float values
__device__ inline unsigned fenc(float f) {
    unsigned u = __float_as_uint(f);
    return (u & 0x80000000u) ? ~u : (u | 0x80000000u);
}
__device__ inline float fdec(unsigned e) {
    return (e & 0x80000000u) ? __uint_as_float(e & 0x7fffffffu)
                             : __uint_as_float(~e);
}

// ---------------------------------------------------------------------------
// k_rowsq: dst[r] = sum(src[r,:]^2) replicating numpy pairwise_sum bit-exactly
// (unchanged from the verified kernel).
__global__ void k_rowsq(const float* __restrict__ src, float* __restrict__ dst,
                        int nrows) {
#pragma clang fp contract(off)
    const int lane = threadIdx.x & 63;
    const int wid = (blockIdx.x * blockDim.x + threadIdx.x) >> 6;
    if (wid >= nrows) return;
    float r = 0.0f;
    if (lane < 16) {
        const int half = lane >> 3, j = lane & 7;
        const float* a = src + (size_t)wid * DD + half * 128 + j;
        float v = a[0];
        r = v * v;
        for (int t = 1; t < 16; ++t) {
            float u = a[8 * t];
            float p = u * u;
            r = r + p;
        }
    }
    float o1 = __shfl_xor(r, 1); r = r + o1;
    float o2 = __shfl_xor(r, 2); r = r + o2;
    float o4 = __shfl_xor(r, 4); r = r + o4;
    float o8 = __shfl_xor(r, 8); r = r + o8;
    if (lane == 0) dst[wid] = r;
}

// ---------------------------------------------------------------------------
// k_prep: build cbh = bf16 codebook in MFMA-B-friendly layout [k/8][code][k%8]
// (fragment read = one contiguous 16B chunk per lane); zero hist / lossAcc.
__global__ void k_prep(const float* __restrict__ cb,
                       unsigned short* __restrict__ cbh,
                       int* __restrict__ hist, float* __restrict__ lossAcc) {
    const int code = blockIdx.x, k = threadIdx.x;
    cbh[(size_t)(k >> 3) * 8192 + code * 8 + (k & 7)] = rne_bf16(cb[code * DD + k]);
    if (code == 0) {
        for (int i = k; i < KK; i += 256) hist[i] = 0;
        if (k == 0) *lossAcc = 0.0f;
    }
}

// ---------------------------------------------------------------------------
// k2_gemm (RESTRUCTURED): bf16 MFMA scores s = c2 - 2*dot, 64 rows x 1024
// codes per block, 8 waves (wave w owns codes w*128..+128).
// Round-5 schedule had 2 barriers + a 32KB bL LDS re-stage per k-step
// (8 MFMA between drains -> MfmaUtil 11.8%). Now: B fragments are per-lane
// contiguous 16B global loads (coalesced 512B/half-wave, L2-resident 512KB
// codebook) loaded straight into registers, double-buffered with NAMED slots
// (static indexing after full unroll). A stays in LDS, read-only after ONE
// barrier. Main loop has ZERO barriers; only counted vmcnt/lgkmcnt waits.
// MFMA order per accumulator unchanged -> bit-identical scores/candidates.
__global__ __launch_bounds__(512, 2) void k2_gemm(
    const float* __restrict__ x, const unsigned short* __restrict__ cbh,
    const float* __restrict__ c2, int* __restrict__ candBuf) {
    __shared__ unsigned short aL[16384];          // [kg 32][row 64][8]  32KB
    __shared__ unsigned wmin[64];
    __shared__ int ccnt[64];
    __shared__ unsigned short clist[64][CAND_MAX];

    const int tid = threadIdx.x;
    const int lane = tid & 63;
    const int w = tid >> 6;                       // wave = code group
    const int row0 = blockIdx.x * 64;
    const int h = lane >> 5;                      // k-half within fragment
    const int l31 = lane & 31;

    if (tid < 64) { wmin[tid] = 0xFFFFFFFFu; ccnt[tid] = 0; }

    {   // stage A: 64 rows x 256 k, fp32 -> bf16 RNE, layout [k/8][row][8]
        const float4* xg = (const float4*)(x + (size_t)row0 * DD);
#pragma unroll
        for (int i = 0; i < 8; ++i) {
            int lin = tid + i * 512;              // 0..4095 float4s
            int r = lin >> 6, c4 = lin & 63;      // k = c4*4..+3
            float4 v = xg[lin];
            unsigned p0 = (unsigned)rne_bf16(v.x) | ((unsigned)rne_bf16(v.y) << 16);
            unsigned p1 = (unsigned)rne_bf16(v.z) | ((unsigned)rne_bf16(v.w) << 16);
            unsigned short* p = &aL[(c4 >> 1) * 512 + r * 8 + (c4 & 1) * 4];
            *(uint2*)p = make_uint2(p0, p1);
        }
    }
    __syncthreads();                              // the ONLY pre-epilogue barrier

    f32x16 acc[2][4];
#pragma unroll
    for (int rf = 0; rf < 2; ++rf)
#pragma unroll
        for (int cf = 0; cf < 4; ++cf)
#pragma unroll
            for (int e = 0; e < 16; ++e) acc[rf][cf][e] = 0.0f;

    // A fragment pointer: chunk (2*ks+h)*64 + l31 (+32 for second row-frag)
    const bf16x8* aptr = (const bf16x8*)aL + h * 64 + l31;
    // B fragment pointer: chunk (2*ks+h)*1024 + w*128 + cf*32 + l31
    const bf16x8* bptr = (const bf16x8*)cbh + (size_t)h * 1024 + w * 128 + l31;

    bf16x8 b0[4], b1[4];                          // named double-buffer slots
#define LDB(KS, B)                                                            \
    do {                                                                      \
        B[0] = bptr[(KS) * 2048];                                             \
        B[1] = bptr[(KS) * 2048 + 32];                                        \
        B[2] = bptr[(KS) * 2048 + 64];                                        \
        B[3] = bptr[(KS) * 2048 + 96];                                        \
    } while (0)

    LDB(0, b0);
    LDB(1, b1);
#pragma unroll
    for (int ks = 0; ks < 16; ks += 2) {
        bf16x8 av0 = aptr[ks * 128];
        bf16x8 av1 = aptr[ks * 128 + 32];
#pragma unroll
        for (int cf = 0; cf < 4; ++cf) {
            acc[0][cf] = __builtin_amdgcn_mfma_f32_32x32x16_bf16(av0, b0[cf], acc[0][cf], 0, 0, 0);
            acc[1][cf] = __builtin_amdgcn_mfma_f32_32x32x16_bf16(av1, b0[cf], acc[1][cf], 0, 0, 0);
        }
        if (ks + 2 < 16) LDB(ks + 2, b0);         // refill after consumption
        bf16x8 aw0 = aptr[(ks + 1) * 128];
        bf16x8 aw1 = aptr[(ks + 1) * 128 + 32];
#pragma unroll
        for (int cf = 0; cf < 4; ++cf) {
            acc[0][cf] = __builtin_amdgcn_mfma_f32_32x32x16_bf16(aw0, b1[cf], acc[0][cf], 0, 0, 0);
            acc[1][cf] = __builtin_amdgcn_mfma_f32_32x32x16_bf16(aw1, b1[cf], acc[1][cf], 0, 0, 0);
        }
        if (ks + 3 < 16) LDB(ks + 3, b1);
    }
#undef LDB

    // scores in place: s = c2_exact - 2*dot_bf16
    float c2v[4];
#pragma unroll
    for (int cf = 0; cf < 4; ++cf) c2v[cf] = c2[w * 128 + cf * 32 + l31];
#pragma unroll
    for (int rf = 0; rf < 2; ++rf)
#pragma unroll
        for (int cf = 0; cf < 4; ++cf)
#pragma unroll
            for (int e = 0; e < 16; ++e)
                acc[rf][cf][e] = fmaf(-2.0f, acc[rf][cf][e], c2v[cf]);

    // pass 1: per-row block-wide min via shfl + LDS atomicMin
#pragma unroll
    for (int rf = 0; rf < 2; ++rf)
#pragma unroll
        for (int r = 0; r < 16; ++r) {
            float v = fminf(fminf(acc[rf][0][r], acc[rf][1][r]),
                            fminf(acc[rf][2][r], acc[rf][3][r]));
            v = fminf(v, __shfl_xor(v, 1));
            v = fminf(v, __shfl_xor(v, 2));
            v = fminf(v, __shfl_xor(v, 4));
            v = fminf(v, __shfl_xor(v, 8));
            v = fminf(v, __shfl_xor(v, 16));
            if (l31 == 0)
                atomicMin(&wmin[rf * 32 + (r & 3) + 8 * (r >> 2) + 4 * h], fenc(v));
        }
    __syncthreads();

    // pass 2: collect candidates within THETA of the row min
#pragma unroll
    for (int rf = 0; rf < 2; ++rf)
#pragma unroll
        for (int r = 0; r < 16; ++r) {
            int rr = rf * 32 + (r & 3) + 8 * (r >> 2) + 4 * h;
            float gm = fdec(wmin[rr]) + THETA;
#pragma unroll
            for (int cf = 0; cf < 4; ++cf) {
                if (acc[rf][cf][r] <= gm) {
                    int pos = atomicAdd(&ccnt[rr], 1);
                    if (pos < CAND_MAX)
                        clist[rr][pos] = (unsigned short)(w * 128 + cf * 32 + l31);
                }
            }
        }
    __syncthreads();

    if (tid < 64) {
        int* o = candBuf + (size_t)(row0 + tid) * (CAND_MAX + 1);
        o[0] = ccnt[tid];
#pragma unroll
        for (int i = 0; i < CAND_MAX; ++i) o[1 + i] = clist[tid][i];
    }
}

// ---------------------------------------------------------------------------
// k_recheck: block-balanced worklist, two-pass exact lexicographic (s,k) min,
// block-cooperative overflow scan (unchanged from round 5 -- verified).
__global__ __launch_bounds__(256) void k_recheck(
    const float* __restrict__ x, const float* __restrict__ cb,
    const float* __restrict__ c2, const int* __restrict__ candBuf,
    float* __restrict__ outIdx, int* __restrict__ hist,
    float* __restrict__ lossAcc) {
#pragma clang fp contract(off)
    __shared__ float xsT[DD * 65];                // [d][row], pad-65: 66,560B
    __shared__ float x2s[64];
    __shared__ unsigned bestS[64];
    __shared__ int bestK[64];
    __shared__ int wl[64 * CAND_MAX];             // (row<<16)|k
    __shared__ float wls[64 * CAND_MAX];          // exact s per item
    __shared__ int ovf[64];
    __shared__ int wln, ovfn;

    const int tid = threadIdx.x;
    const int row0 = blockIdx.x * 64;

    if (tid < 64) { bestS[tid] = 0xFFFFFFFFu; bestK[tid] = 0x7fffffff; }
    if (tid == 0) { wln = 0; ovfn = 0; }

    {   // stage 64 rows transposed
        const float4* xg = (const float4*)(x + (size_t)row0 * DD);
#pragma unroll
        for (int i = 0; i < 16; ++i) {
            int lin = tid + i * 256;
            int r = lin >> 6, c4 = lin & 63;
            float4 v = xg[lin];
            xsT[(c4 * 4 + 0) * 65 + r] = v.x;
            xsT[(c4 * 4 + 1) * 65 + r] = v.y;
            xsT[(c4 * 4 + 2) * 65 + r] = v.z;
            xsT[(c4 * 4 + 3) * 65 + r] = v.w;
        }
    }
    __syncthreads();

    // exact x2 per row (np pairwise lattice) + worklist build
    if (tid < 64) {
        const int row = tid;
        float hsum[2];
#pragma unroll
        for (int hh = 0; hh < 2; ++hh) {
            float a[8];
#pragma unroll
            for (int j = 0; j < 8; ++j) {
                float v = xsT[(hh * 128 + j) * 65 + row];
                a[j] = v * v;
            }
            for (int t = 1; t < 16; ++t) {
#pragma unroll
                for (int j = 0; j < 8; ++j) {
                    float u = xsT[(hh * 128 + j + 8 * t) * 65 + row];
                    float p = u * u;
                    a[j] = a[j] + p;
                }
            }
            float s01 = a[0] + a[1], s23 = a[2] + a[3];
            float s45 = a[4] + a[5], s67 = a[6] + a[7];
            hsum[hh] = (s01 + s23) + (s45 + s67);
        }
        x2s[row] = hsum[0] + hsum[1];

        const int* cd = candBuf + (size_t)(row0 + row) * (CAND_MAX + 1);
        int n = cd[0];
        if (n <= CAND_MAX) {
            int base = atomicAdd(&wln, n);
            for (int i = 0; i < n; ++i) wl[base + i] = (row << 16) | cd[1 + i];
        } else {
            ovf[atomicAdd(&ovfn, 1)] = row;       // incomplete list: full scan
        }
    }
    __syncthreads();

    const int NW = wln;
    const int NO = ovfn;

    // pass A: exact s per item, per-row min via encoded atomicMin
    for (int it = tid; it < NW; it += 256) {
        const int row = wl[it] >> 16, k = wl[it] & 0xFFFF;
        const float* cr = cb + (size_t)k * DD;
        float dot = 0.0f;
#pragma unroll 8
        for (int d = 0; d < DD; ++d)
            dot = fmaf(xsT[d * 65 + row], cr[d], dot);
        float T1 = x2s[row] + c2[k];
        float s = fmaf(-2.0f, dot, T1);
        wls[it] = s;
        atomicMin(&bestS[row], fenc(s));
    }
    __syncthreads();

    // pass B: smallest index among s == row min (first-index argmin)
    for (int it = tid; it < NW; it += 256) {
        const int row = wl[it] >> 16, k = wl[it] & 0xFFFF;
        if (fenc(wls[it]) == bestS[row]) atomicMin(&bestK[row], k);
    }

    // overflow rows: block-cooperative exact full scan (4 codes per thread)
    for (int o = 0; o < NO; ++o) {
        __syncthreads();
        const int row = ovf[o];
        float myS[4];
#pragma unroll
        for (int q = 0; q < 4; ++q) {
            const int k = tid + q * 256;
            const float* cr = cb + (size_t)k * DD;
            float dot = 0.0f;
#pragma unroll 8
            for (int d = 0; d < DD; ++d)
                dot = fmaf(xsT[d * 65 + row], cr[d], dot);   // LDS broadcast
            float T1 = x2s[row] + c2[k];
            myS[q] = fmaf(-2.0f, dot, T1);
            atomicMin(&bestS[row], fenc(myS[q]));
        }
        __syncthreads();
#pragma unroll
        for (int q = 0; q < 4; ++q)
            if (fenc(myS[q]) == bestS[row]) atomicMin(&bestK[row], tid + q * 256);
    }
    __syncthreads();

    if (tid < 64) {
        const float bs = fdec(bestS[tid]);
        const int bk = bestK[tid];
        outIdx[row0 + tid] = (float)bk;
        atomicAdd(hist + bk, 1);
        float ls = bs;
#pragma unroll
        for (int off = 32; off > 0; off >>= 1) ls += __shfl_down(ls, off);
        if (tid == 0) atomicAdd(lossAcc, ls);
    }
}

// ---------------------------------------------------------------------------
// K3: pure gather -> outQ (unchanged).
__global__ __launch_bounds__(256) void k3_gather(
    const float* __restrict__ cb, const float* __restrict__ outIdx,
    float* __restrict__ outQ) {
    __shared__ int sidx[ROWS_PB];
    const int t = threadIdx.x;
    const int row0 = blockIdx.x * ROWS_PB;
    if (t < ROWS_PB) sidx[t] = (int)outIdx[row0 + t];
    __syncthreads();

    float4* q4 = (float4*)(outQ + (size_t)row0 * DD);
    const float4* c4 = (const float4*)cb;
#pragma unroll
    for (int i = 0; i < 16; ++i) {
        int lin = t + i * 256;
        int r = lin >> 6;
        int c = lin & 63;
        q4[lin] = c4[(size_t)sidx[r] * 64 + c];
    }
}

// ---------------------------------------------------------------------------
// K4: finalize loss + perplexity (unchanged).
__global__ void k4_final(const int* __restrict__ hist,
                         const float* __restrict__ lossAcc,
                         float* __restrict__ outLoss,
                         float* __restrict__ outPerp) {
    __shared__ float red[256];
    const int t = threadIdx.x;
    float e = 0.0f;
    for (int i = t; i < KK; i += 256) {
        float p = (float)hist[i] * (1.0f / (float)NROWS);
        e -= p * logf(p + 1e-10f);
    }
    red[t] = e;
    __syncthreads();
    for (int s = 128; s > 0; s >>= 1) {
        if (t < s) red[t] += red[t + s];
        __syncthreads();
    }
    if (t == 0) {
        *outPerp = expf(red[0]);
        *outLoss = 1.25f * (*lossAcc) / (float)QELEMS;
    }
}

// ---------------------------------------------------------------------------
extern "C" void kernel_launch(void* const* d_in, const int* in_sizes, int n_in,
                              void* d_out, int out_size, void* d_ws, size_t ws_size,
                              hipStream_t stream) {
    const float* x = (const float*)d_in[0];    // [131072, 256]
    const float* cb = (const float*)d_in[1];   // [1024, 256]

    float* outQ = (float*)d_out;               // 33554432
    float* outIdx = outQ + QELEMS;             // 131072
    float* outLoss = outIdx + NROWS;           // 1
    float* outPerp = outLoss + 1;              // 1

    // ws (~532KB): cbh bf16 [32][1024][8], c2, hist, lossAcc
    unsigned short* cbh = (unsigned short*)d_ws;
    float* c2 = (float*)((char*)d_ws + 524288);
    int* hist = (int*)(c2 + KK);
    float* lossAcc = (float*)(hist + KK);
    // candidate buffer lives in outQ's space (8.9MB of 128MB); it is fully
    // consumed by k_recheck before k3_gather overwrites outQ (stream order).
    int* candBuf = (int*)outQ;

    k_rowsq<<<dim3(KK / 4), dim3(256), 0, stream>>>(cb, c2, KK);
    k_prep<<<dim3(KK), dim3(256), 0, stream>>>(cb, cbh, hist, lossAcc);
    k2_gemm<<<dim3(NROWS / 64), dim3(512), 0, stream>>>(x, cbh, c2, candBuf);
    k_recheck<<<dim3(NROWS / 64), dim3(256), 0, stream>>>(x, cb, c2, candBuf,
                                                          outIdx, hist, lossAcc);
    k3_gather<<<dim3(NROWS / ROWS_PB), dim3(256), 0, stream>>>(cb, outIdx, outQ);
    k4_final<<<dim3(1), dim3(256), 0, stream>>>(hist, lossAcc, outLoss, outPerp);
}

// Round 7
// 532.983 us; speedup vs baseline: 7.6590x; 1.0068x over previous
//
#include <hip/hip_runtime.h>
#include <cfloat>

// Problem constants (fixed by setup_inputs): B=64, S=2048, D=256, K=1024
#define DD 256
#define KK 1024
#define NROWS 131072            // B*S
#define QELEMS 33554432         // NROWS*DD
#define ROWS_PB 64
#define THETA 12.0f             // >= 2*eps_max(bf16 dot) ~ 3.8; 3x margin
#define CAND_MAX 16

typedef __attribute__((ext_vector_type(8))) short bf16x8;    // 8 bf16 = 4 VGPR
typedef __attribute__((ext_vector_type(16))) float f32x16;   // 32x32 acc

// round-to-nearest-even fp32 -> bf16
__device__ inline unsigned short rne_bf16(float f) {
    unsigned u = __float_as_uint(f);
    unsigned r = (u + 0x7fffu + ((u >> 16) & 1u)) >> 16;
    return (unsigned short)r;
}
// monotone float<->uint encoding for atomicMin on float values
__device__ inline unsigned fenc(float f) {
    unsigned u = __float_as_uint(f);
    return (u & 0x80000000u) ? ~u : (u | 0x80000000u);
}
__device__ inline float fdec(unsigned e) {
    return (e & 0x80000000u) ? __uint_as_float(e & 0x7fffffffu)
                             : __uint_as_float(~e);
}

// ---------------------------------------------------------------------------
// k_rowsq: dst[r] = sum(src[r,:]^2) replicating numpy pairwise_sum bit-exactly
// (unchanged from the verified kernel).
__global__ void k_rowsq(const float* __restrict__ src, float* __restrict__ dst,
                        int nrows) {
#pragma clang fp contract(off)
    const int lane = threadIdx.x & 63;
    const int wid = (blockIdx.x * blockDim.x + threadIdx.x) >> 6;
    if (wid >= nrows) return;
    float r = 0.0f;
    if (lane < 16) {
        const int half = lane >> 3, j = lane & 7;
        const float* a = src + (size_t)wid * DD + half * 128 + j;
        float v = a[0];
        r = v * v;
        for (int t = 1; t < 16; ++t) {
            float u = a[8 * t];
            float p = u * u;
            r = r + p;
        }
    }
    float o1 = __shfl_xor(r, 1); r = r + o1;
    float o2 = __shfl_xor(r, 2); r = r + o2;
    float o4 = __shfl_xor(r, 4); r = r + o4;
    float o8 = __shfl_xor(r, 8); r = r + o8;
    if (lane == 0) dst[wid] = r;
}

// ---------------------------------------------------------------------------
// k_prep: build cbh = bf16 codebook in MFMA-B-friendly layout [k/8][code][k%8]
// (fragment read = one contiguous 16B chunk per lane); zero hist / lossAcc.
__global__ void k_prep(const float* __restrict__ cb,
                       unsigned short* __restrict__ cbh,
                       int* __restrict__ hist, float* __restrict__ lossAcc) {
    const int code = blockIdx.x, k = threadIdx.x;
    cbh[(size_t)(k >> 3) * 8192 + code * 8 + (k & 7)] = rne_bf16(cb[code * DD + k]);
    if (code == 0) {
        for (int i = k; i < KK; i += 256) hist[i] = 0;
        if (k == 0) *lossAcc = 0.0f;
    }
}

// ---------------------------------------------------------------------------
// k2_gemm (v3): bf16 MFMA scores s = c2 - 2*dot, 64 rows x 1024 codes/block,
// 8 waves (wave w owns codes w*128..+128).
// R5 vs R6 showed barriers/LDS-restage weren't the cost: both stall on the
// B stream's short issue-to-use distance (8 MFMA ~ 64cy vs ~250cy L2
// latency, 2 waves/SIMD). Changes here:
//  (1) 4-deep NAMED B register buffers (b0..b3, compile-time indexed):
//      refill targets ks+4 -> issue-to-use = 3 steps of MFMA (~192cy) and
//      ~12-16 loads stay in flight (counted vmcnt, never drained).
//  (2) aL chunk XOR-swizzle (chunk = kg*64 + (row^(kg&7))), applied on both
//      write and read: staging writes go from one 4-bank group (~32-way
//      conflict, the 3.7M counter) to 8 groups (~4-way). Reads keep their
//      conflict-free pattern (constant XOR per step).
// MFMA accumulation order per acc[rf][cf] unchanged -> bit-identical scores.
__global__ __launch_bounds__(512, 2) void k2_gemm(
    const float* __restrict__ x, const unsigned short* __restrict__ cbh,
    const float* __restrict__ c2, int* __restrict__ candBuf) {
    __shared__ unsigned short aL[16384];          // [kg 32][row-swz 64][8] 32KB
    __shared__ unsigned wmin[64];
    __shared__ int ccnt[64];
    __shared__ unsigned short clist[64][CAND_MAX];

    const int tid = threadIdx.x;
    const int lane = tid & 63;
    const int w = tid >> 6;                       // wave = code group
    const int row0 = blockIdx.x * 64;
    const int h = lane >> 5;                      // k-half within fragment
    const int l31 = lane & 31;

    if (tid < 64) { wmin[tid] = 0xFFFFFFFFu; ccnt[tid] = 0; }

    {   // stage A: 64 rows x 256 k, fp32 -> bf16 RNE, swizzled [kg][row^][8]
        const float4* xg = (const float4*)(x + (size_t)row0 * DD);
#pragma unroll
        for (int i = 0; i < 8; ++i) {
            int lin = tid + i * 512;              // 0..4095 float4s
            int r = lin >> 6, c4 = lin & 63;      // k = c4*4..+3
            float4 v = xg[lin];
            unsigned p0 = (unsigned)rne_bf16(v.x) | ((unsigned)rne_bf16(v.y) << 16);
            unsigned p1 = (unsigned)rne_bf16(v.z) | ((unsigned)rne_bf16(v.w) << 16);
            int kg = c4 >> 1;
            unsigned short* p = &aL[(kg * 64 + (r ^ (kg & 7))) * 8 + (c4 & 1) * 4];
            *(uint2*)p = make_uint2(p0, p1);
        }
    }
    __syncthreads();                              // the ONLY pre-epilogue barrier

    f32x16 acc[2][4];
#pragma unroll
    for (int rf = 0; rf < 2; ++rf)
#pragma unroll
        for (int cf = 0; cf < 4; ++cf)
#pragma unroll
            for (int e = 0; e < 16; ++e) acc[rf][cf][e] = 0.0f;

    const bf16x8* ab = (const bf16x8*)aL;
    // B fragment pointer: chunk (2*ks+h)*1024 + w*128 + cf*32 + l31
    const bf16x8* bptr = (const bf16x8*)cbh + (size_t)h * 1024 + w * 128 + l31;

    bf16x8 b0[4], b1[4], b2[4], b3[4];            // named 4-deep pipeline
#define LDB(KS, B)                                                            \
    do {                                                                      \
        B[0] = bptr[(KS) * 2048];                                             \
        B[1] = bptr[(KS) * 2048 + 32];                                        \
        B[2] = bptr[(KS) * 2048 + 64];                                        \
        B[3] = bptr[(KS) * 2048 + 96];                                        \
    } while (0)

#define STEP(KS, B)                                                           \
    do {                                                                      \
        const int kg = 2 * (KS) + h;                                          \
        const int rsw = l31 ^ (kg & 7);                                       \
        bf16x8 av0 = ab[kg * 64 + rsw];                                       \
        bf16x8 av1 = ab[kg * 64 + rsw + 32];                                  \
        acc[0][0] = __builtin_amdgcn_mfma_f32_32x32x16_bf16(av0, B[0], acc[0][0], 0, 0, 0); \
        acc[1][0] = __builtin_amdgcn_mfma_f32_32x32x16_bf16(av1, B[0], acc[1][0], 0, 0, 0); \
        acc[0][1] = __builtin_amdgcn_mfma_f32_32x32x16_bf16(av0, B[1], acc[0][1], 0, 0, 0); \
        acc[1][1] = __builtin_amdgcn_mfma_f32_32x32x16_bf16(av1, B[1], acc[1][1], 0, 0, 0); \
        acc[0][2] = __builtin_amdgcn_mfma_f32_32x32x16_bf16(av0, B[2], acc[0][2], 0, 0, 0); \
        acc[1][2] = __builtin_amdgcn_mfma_f32_32x32x16_bf16(av1, B[2], acc[1][2], 0, 0, 0); \
        acc[0][3] = __builtin_amdgcn_mfma_f32_32x32x16_bf16(av0, B[3], acc[0][3], 0, 0, 0); \
        acc[1][3] = __builtin_amdgcn_mfma_f32_32x32x16_bf16(av1, B[3], acc[1][3], 0, 0, 0); \
        if ((KS) + 4 < 16) LDB((KS) + 4, B);                                  \
    } while (0)

    LDB(0, b0); LDB(1, b1); LDB(2, b2); LDB(3, b3);
#pragma unroll
    for (int ks = 0; ks < 16; ks += 4) {
        STEP(ks + 0, b0);
        STEP(ks + 1, b1);
        STEP(ks + 2, b2);
        STEP(ks + 3, b3);
    }
#undef STEP
#undef LDB

    // scores in place: s = c2_exact - 2*dot_bf16
    float c2v[4];
#pragma unroll
    for (int cf = 0; cf < 4; ++cf) c2v[cf] = c2[w * 128 + cf * 32 + l31];
#pragma unroll
    for (int rf = 0; rf < 2; ++rf)
#pragma unroll
        for (int cf = 0; cf < 4; ++cf)
#pragma unroll
            for (int e = 0; e < 16; ++e)
                acc[rf][cf][e] = fmaf(-2.0f, acc[rf][cf][e], c2v[cf]);

    // pass 1: per-row block-wide min via shfl + LDS atomicMin
#pragma unroll
    for (int rf = 0; rf < 2; ++rf)
#pragma unroll
        for (int r = 0; r < 16; ++r) {
            float v = fminf(fminf(acc[rf][0][r], acc[rf][1][r]),
                            fminf(acc[rf][2][r], acc[rf][3][r]));
            v = fminf(v, __shfl_xor(v, 1));
            v = fminf(v, __shfl_xor(v, 2));
            v = fminf(v, __shfl_xor(v, 4));
            v = fminf(v, __shfl_xor(v, 8));
            v = fminf(v, __shfl_xor(v, 16));
            if (l31 == 0)
                atomicMin(&wmin[rf * 32 + (r & 3) + 8 * (r >> 2) + 4 * h], fenc(v));
        }
    __syncthreads();

    // pass 2: collect candidates within THETA of the row min
#pragma unroll
    for (int rf = 0; rf < 2; ++rf)
#pragma unroll
        for (int r = 0; r < 16; ++r) {
            int rr = rf * 32 + (r & 3) + 8 * (r >> 2) + 4 * h;
            float gm = fdec(wmin[rr]) + THETA;
#pragma unroll
            for (int cf = 0; cf < 4; ++cf) {
                if (acc[rf][cf][r] <= gm) {
                    int pos = atomicAdd(&ccnt[rr], 1);
                    if (pos < CAND_MAX)
                        clist[rr][pos] = (unsigned short)(w * 128 + cf * 32 + l31);
                }
            }
        }
    __syncthreads();

    if (tid < 64) {
        int* o = candBuf + (size_t)(row0 + tid) * (CAND_MAX + 1);
        o[0] = ccnt[tid];
#pragma unroll
        for (int i = 0; i < CAND_MAX; ++i) o[1 + i] = clist[tid][i];
    }
}

// ---------------------------------------------------------------------------
// k_recheck: block-balanced worklist, two-pass exact lexicographic (s,k) min,
// block-cooperative overflow scan (unchanged -- verified).
__global__ __launch_bounds__(256) void k_recheck(
    const float* __restrict__ x, const float* __restrict__ cb,
    const float* __restrict__ c2, const int* __restrict__ candBuf,
    float* __restrict__ outIdx, int* __restrict__ hist,
    float* __restrict__ lossAcc) {
#pragma clang fp contract(off)
    __shared__ float xsT[DD * 65];                // [d][row], pad-65: 66,560B
    __shared__ float x2s[64];
    __shared__ unsigned bestS[64];
    __shared__ int bestK[64];
    __shared__ int wl[64 * CAND_MAX];             // (row<<16)|k
    __shared__ float wls[64 * CAND_MAX];          // exact s per item
    __shared__ int ovf[64];
    __shared__ int wln, ovfn;

    const int tid = threadIdx.x;
    const int row0 = blockIdx.x * 64;

    if (tid < 64) { bestS[tid] = 0xFFFFFFFFu; bestK[tid] = 0x7fffffff; }
    if (tid == 0) { wln = 0; ovfn = 0; }

    {   // stage 64 rows transposed
        const float4* xg = (const float4*)(x + (size_t)row0 * DD);
#pragma unroll
        for (int i = 0; i < 16; ++i) {
            int lin = tid + i * 256;
            int r = lin >> 6, c4 = lin & 63;
            float4 v = xg[lin];
            xsT[(c4 * 4 + 0) * 65 + r] = v.x;
            xsT[(c4 * 4 + 1) * 65 + r] = v.y;
            xsT[(c4 * 4 + 2) * 65 + r] = v.z;
            xsT[(c4 * 4 + 3) * 65 + r] = v.w;
        }
    }
    __syncthreads();

    // exact x2 per row (np pairwise lattice) + worklist build
    if (tid < 64) {
        const int row = tid;
        float hsum[2];
#pragma unroll
        for (int hh = 0; hh < 2; ++hh) {
            float a[8];
#pragma unroll
            for (int j = 0; j < 8; ++j) {
                float v = xsT[(hh * 128 + j) * 65 + row];
                a[j] = v * v;
            }
            for (int t = 1; t < 16; ++t) {
#pragma unroll
                for (int j = 0; j < 8; ++j) {
                    float u = xsT[(hh * 128 + j + 8 * t) * 65 + row];
                    float p = u * u;
                    a[j] = a[j] + p;
                }
            }
            float s01 = a[0] + a[1], s23 = a[2] + a[3];
            float s45 = a[4] + a[5], s67 = a[6] + a[7];
            hsum[hh] = (s01 + s23) + (s45 + s67);
        }
        x2s[row] = hsum[0] + hsum[1];

        const int* cd = candBuf + (size_t)(row0 + row) * (CAND_MAX + 1);
        int n = cd[0];
        if (n <= CAND_MAX) {
            int base = atomicAdd(&wln, n);
            for (int i = 0; i < n; ++i) wl[base + i] = (row << 16) | cd[1 + i];
        } else {
            ovf[atomicAdd(&ovfn, 1)] = row;       // incomplete list: full scan
        }
    }
    __syncthreads();

    const int NW = wln;
    const int NO = ovfn;

    // pass A: exact s per item, per-row min via encoded atomicMin
    for (int it = tid; it < NW; it += 256) {
        const int row = wl[it] >> 16, k = wl[it] & 0xFFFF;
        const float* cr = cb + (size_t)k * DD;
        float dot = 0.0f;
#pragma unroll 8
        for (int d = 0; d < DD; ++d)
            dot = fmaf(xsT[d * 65 + row], cr[d], dot);
        float T1 = x2s[row] + c2[k];
        float s = fmaf(-2.0f, dot, T1);
        wls[it] = s;
        atomicMin(&bestS[row], fenc(s));
    }
    __syncthreads();

    // pass B: smallest index among s == row min (first-index argmin)
    for (int it = tid; it < NW; it += 256) {
        const int row = wl[it] >> 16, k = wl[it] & 0xFFFF;
        if (fenc(wls[it]) == bestS[row]) atomicMin(&bestK[row], k);
    }

    // overflow rows: block-cooperative exact full scan (4 codes per thread)
    for (int o = 0; o < NO; ++o) {
        __syncthreads();
        const int row = ovf[o];
        float myS[4];
#pragma unroll
        for (int q = 0; q < 4; ++q) {
            const int k = tid + q * 256;
            const float* cr = cb + (size_t)k * DD;
            float dot = 0.0f;
#pragma unroll 8
            for (int d = 0; d < DD; ++d)
                dot = fmaf(xsT[d * 65 + row], cr[d], dot);   // LDS broadcast
            float T1 = x2s[row] + c2[k];
            myS[q] = fmaf(-2.0f, dot, T1);
            atomicMin(&bestS[row], fenc(myS[q]));
        }
        __syncthreads();
#pragma unroll
        for (int q = 0; q < 4; ++q)
            if (fenc(myS[q]) == bestS[row]) atomicMin(&bestK[row], tid + q * 256);
    }
    __syncthreads();

    if (tid < 64) {
        const float bs = fdec(bestS[tid]);
        const int bk = bestK[tid];
        outIdx[row0 + tid] = (float)bk;
        atomicAdd(hist + bk, 1);
        float ls = bs;
#pragma unroll
        for (int off = 32; off > 0; off >>= 1) ls += __shfl_down(ls, off);
        if (tid == 0) atomicAdd(lossAcc, ls);
    }
}

// ---------------------------------------------------------------------------
// K3: pure gather -> outQ (unchanged).
__global__ __launch_bounds__(256) void k3_gather(
    const float* __restrict__ cb, const float* __restrict__ outIdx,
    float* __restrict__ outQ) {
    __shared__ int sidx[ROWS_PB];
    const int t = threadIdx.x;
    const int row0 = blockIdx.x * ROWS_PB;
    if (t < ROWS_PB) sidx[t] = (int)outIdx[row0 + t];
    __syncthreads();

    float4* q4 = (float4*)(outQ + (size_t)row0 * DD);
    const float4* c4 = (const float4*)cb;
#pragma unroll
    for (int i = 0; i < 16; ++i) {
        int lin = t + i * 256;
        int r = lin >> 6;
        int c = lin & 63;
        q4[lin] = c4[(size_t)sidx[r] * 64 + c];
    }
}

// ---------------------------------------------------------------------------
// K4: finalize loss + perplexity (unchanged).
__global__ void k4_final(const int* __restrict__ hist,
                         const float* __restrict__ lossAcc,
                         float* __restrict__ outLoss,
                         float* __restrict__ outPerp) {
    __shared__ float red[256];
    const int t = threadIdx.x;
    float e = 0.0f;
    for (int i = t; i < KK; i += 256) {
        float p = (float)hist[i] * (1.0f / (float)NROWS);
        e -= p * logf(p + 1e-10f);
    }
    red[t] = e;
    __syncthreads();
    for (int s = 128; s > 0; s >>= 1) {
        if (t < s) red[t] += red[t + s];
        __syncthreads();
    }
    if (t == 0) {
        *outPerp = expf(red[0]);
        *outLoss = 1.25f * (*lossAcc) / (float)QELEMS;
    }
}

// ---------------------------------------------------------------------------
extern "C" void kernel_launch(void* const* d_in, const int* in_sizes, int n_in,
                              void* d_out, int out_size, void* d_ws, size_t ws_size,
                              hipStream_t stream) {
    const float* x = (const float*)d_in[0];    // [131072, 256]
    const float* cb = (const float*)d_in[1];   // [1024, 256]

    float* outQ = (float*)d_out;               // 33554432
    float* outIdx = outQ + QELEMS;             // 131072
    float* outLoss = outIdx + NROWS;           // 1
    float* outPerp = outLoss + 1;              // 1

    // ws (~532KB): cbh bf16 [32][1024][8], c2, hist, lossAcc
    unsigned short* cbh = (unsigned short*)d_ws;
    float* c2 = (float*)((char*)d_ws + 524288);
    int* hist = (int*)(c2 + KK);
    float* lossAcc = (float*)(hist + KK);
    // candidate buffer lives in outQ's space (8.9MB of 128MB); it is fully
    // consumed by k_recheck before k3_gather overwrites outQ (stream order).
    int* candBuf = (int*)outQ;

    k_rowsq<<<dim3(KK / 4), dim3(256), 0, stream>>>(cb, c2, KK);
    k_prep<<<dim3(KK), dim3(256), 0, stream>>>(cb, cbh, hist, lossAcc);
    k2_gemm<<<dim3(NROWS / 64), dim3(512), 0, stream>>>(x, cbh, c2, candBuf);
    k_recheck<<<dim3(NROWS / 64), dim3(256), 0, stream>>>(x, cb, c2, candBuf,
                                                          outIdx, hist, lossAcc);
    k3_gather<<<dim3(NROWS / ROWS_PB), dim3(256), 0, stream>>>(cb, outIdx, outQ);
    k4_final<<<dim3(1), dim3(256), 0, stream>>>(hist, lossAcc, outLoss, outPerp);
}